// Round 19
// baseline (163.984 us; speedup 1.0000x reference)
//
#include <hip/hip_runtime.h>
#include <math.h>

// Problem constants
#define B_   64
#define IC_  4096
#define NC_  16
#define D_   16
#define IPB  8     // i's per block -> NI = 512
#define XROW 34    // u32 per x-LDS batch row (8 i x 4 u32 + 2 pad)

typedef __fp16 half8  __attribute__((ext_vector_type(8)));
typedef __fp16 half2v __attribute__((ext_vector_type(2)));
typedef float  f32x4  __attribute__((ext_vector_type(4)));

// pack 2 fp32 -> half2 in a u32 (v_cvt_pkrtz_f32_f16)
__device__ inline unsigned pk16(float a, float b) {
    half2v h = __builtin_amdgcn_cvt_pkrtz(a, b);
    return __builtin_bit_cast(unsigned, h);
}
// f32 += dot(half2, half2)  (v_dot2_f32_f16)
__device__ inline float hdot2(unsigned w, unsigned x, float c) {
    return __builtin_amdgcn_fdot2(__builtin_bit_cast(half2v, w),
                                  __builtin_bit_cast(half2v, x), c, false);
}
__device__ inline half8 h8(uint4 v) { return __builtin_bit_cast(half8, v); }

// Single-sweep MFMA pass (layouts HW-verified in R17/R18).
// Block = 512 thr (8 waves) = 4 btiles x 2 ihalves; IPB=8 i's per block.
// W staged once to LDS in A-fragment order [il][jq][q][row16][4u32]
// (row packs (j&3)*4+(d&3)); x staged as f16 [b][i][4u32].
// Per i: 16 MFMAs (K=8 of 32, zero-padded lanes>=16) give
// uh[j=4jq+g][d=4q+reg][b=l15] held in C regs; logits via in-lane
// pk16+hdot2 vs prescaled osum; softmax = 4 exp2 + xor16 + xor32;
// acc += cc*C from held registers (NO recompute - the R17 fix).
// use_osum=0: MFMA accumulates straight into acc (uniform c = 1/16 at store).
__global__ __launch_bounds__(512)
void caps_mpass(const float* __restrict__ inp, const float* __restrict__ W,
                const float* __restrict__ osum, unsigned* __restrict__ partials,
                int use_osum)
{
    __shared__ unsigned wlds[8192];      // 32 KB: [il8][jq4][q4][row16][4]
    __shared__ unsigned xlds[64 * XROW]; // 8.7 KB

    const int tid   = threadIdx.x;
    const int lane  = tid & 63;
    const int l15   = lane & 15;
    const int g     = lane >> 4;
    const int wv    = tid >> 6;
    const int btile = wv & 3;
    const int ihalf = wv >> 2;

    // XCD-aware bijective swizzle (grid = 512, divisible by 8)
    const int n   = blockIdx.x;
    const int cpx = gridDim.x >> 3;
    const int ib  = (n & 7) * cpx + (n >> 3);
    const int i0  = ib * IPB;

    // ---- stage x: tid -> (b = tid>>3, io = tid&7), 8 f32 -> 4 u32 ----
    {
        const int xb = tid >> 3, io = tid & 7;
        const float4* src = (const float4*)inp + ((size_t)xb * IC_ + i0 + io) * 2;
        float4 a = src[0], b = src[1];
        *(uint4*)&xlds[xb * XROW + io * 4] =
            make_uint4(pk16(a.x, a.y), pk16(a.z, a.w), pk16(b.x, b.y), pk16(b.z, b.w));
    }
    // ---- stage W in A-frag order (R17-verified) ----
    {
        const float4* Wf4 = (const float4*)W;
#pragma unroll
        for (int it = 0; it < 4; ++it) {
            int u  = it * 512 + tid;
            int il = u >> 8, j = (u >> 4) & 15, d = u & 15;
            size_t gidx = (((size_t)j * IC_ + i0 + il) * 16 + d) * 2;
            float4 a = Wf4[gidx], b = Wf4[gidx + 1];
            int widx = ((il * 4 + (j >> 2)) * 4 + (d >> 2)) * 64 + ((j & 3) * 4 + (d & 3)) * 4;
            *(uint4*)&wlds[widx] =
                make_uint4(pk16(a.x, a.y), pk16(a.z, a.w), pk16(b.x, b.y), pk16(b.z, b.w));
        }
    }
    __syncthreads();

    const int b16 = btile * 16 + l15;
    const f32x4 zero4 = {0.f, 0.f, 0.f, 0.f};
    const bool lo = lane < 16;

    f32x4 acc[4][4];
#pragma unroll
    for (int a1 = 0; a1 < 4; ++a1)
#pragma unroll
        for (int a2 = 0; a2 < 4; ++a2) acc[a1][a2] = zero4;

    if (!use_osum) {
        // uniform c: MFMA straight into acc; 1/16 folded into store
#pragma unroll
        for (int ii = 0; ii < 4; ++ii) {
            const int il = ihalf * 4 + ii;
            uint4 xf = make_uint4(0, 0, 0, 0);
            if (lo) xf = *(const uint4*)&xlds[b16 * XROW + il * 4];
            half8 xb8 = h8(xf);
#pragma unroll
            for (int jq = 0; jq < 4; ++jq)
#pragma unroll
                for (int q = 0; q < 4; ++q) {
                    uint4 wf = make_uint4(0, 0, 0, 0);
                    if (lo) wf = *(const uint4*)&wlds[((il * 4 + jq) * 4 + q) * 64 + l15 * 4];
                    acc[jq][q] = __builtin_amdgcn_mfma_f32_16x16x32_f16(
                        h8(wf), xb8, acc[jq][q], 0, 0, 0);
                }
        }
    } else {
        // osum prologue: lane's b=b16, j-family {4jq+g}, 16 d, prescaled log2(e)
        unsigned osh[4][8];
        const float L2E = 1.44269504f;
#pragma unroll
        for (int jq = 0; jq < 4; ++jq) {
            const float4* op = (const float4*)osum + ((size_t)b16 * 16 + 4 * jq + g) * 4;
#pragma unroll
            for (int q = 0; q < 4; ++q) {
                float4 o = op[q];
                osh[jq][q * 2]     = pk16(o.x * L2E, o.y * L2E);
                osh[jq][q * 2 + 1] = pk16(o.z * L2E, o.w * L2E);
            }
        }
#pragma unroll
        for (int ii = 0; ii < 4; ++ii) {
            const int il = ihalf * 4 + ii;
            uint4 xf = make_uint4(0, 0, 0, 0);
            if (lo) xf = *(const uint4*)&xlds[b16 * XROW + il * 4];
            half8 xb8 = h8(xf);

            // compute + HOLD all 16 uh tiles
            f32x4 C[4][4];
#pragma unroll
            for (int jq = 0; jq < 4; ++jq)
#pragma unroll
                for (int q = 0; q < 4; ++q) {
                    uint4 wf = make_uint4(0, 0, 0, 0);
                    if (lo) wf = *(const uint4*)&wlds[((il * 4 + jq) * 4 + q) * 64 + l15 * 4];
                    C[jq][q] = __builtin_amdgcn_mfma_f32_16x16x32_f16(
                        h8(wf), xb8, zero4, 0, 0, 0);
                }

            // logits: pb[jq] = osum . uh  (in-lane, f16 dots)
            float pb[4];
#pragma unroll
            for (int jq = 0; jq < 4; ++jq) {
                float t = 0.f;
#pragma unroll
                for (int q = 0; q < 4; ++q) {
                    unsigned p0 = pk16(C[jq][q][0], C[jq][q][1]);
                    unsigned p1 = pk16(C[jq][q][2], C[jq][q][3]);
                    t = hdot2(osh[jq][q * 2], p0, t);
                    t = hdot2(osh[jq][q * 2 + 1], p1, t);
                }
                pb[jq] = t;
            }
            // softmax over 16 j (4 in-lane + cross-group xor16/32)
            float e0 = exp2f(pb[0]), e1 = exp2f(pb[1]);
            float e2 = exp2f(pb[2]), e3 = exp2f(pb[3]);
            float den = (e0 + e1) + (e2 + e3);
            den += __shfl_xor(den, 16);
            den += __shfl_xor(den, 32);
            float r = __fdividef(1.f, den);
            float cc[4] = {e0 * r, e1 * r, e2 * r, e3 * r};

            // accumulate from HELD registers
#pragma unroll
            for (int jq = 0; jq < 4; ++jq)
#pragma unroll
                for (int q = 0; q < 4; ++q) {
                    acc[jq][q][0] = fmaf(cc[jq], C[jq][q][0], acc[jq][q][0]);
                    acc[jq][q][1] = fmaf(cc[jq], C[jq][q][1], acc[jq][q][1]);
                    acc[jq][q][2] = fmaf(cc[jq], C[jq][q][2], acc[jq][q][2]);
                    acc[jq][q][3] = fmaf(cc[jq], C[jq][q][3], acc[jq][q][3]);
                }
        }
    }

    // ---- combine the two i-halves via LDS (wlds reuse), store f16 partials ----
    __syncthreads();
    if (ihalf == 1) {
        unsigned* dst = &wlds[(btile * 64 + lane) * 32];
#pragma unroll
        for (int jq = 0; jq < 4; ++jq)
#pragma unroll
            for (int q = 0; q < 4; ++q) {
                dst[(jq * 4 + q) * 2]     = pk16(acc[jq][q][0], acc[jq][q][1]);
                dst[(jq * 4 + q) * 2 + 1] = pk16(acc[jq][q][2], acc[jq][q][3]);
            }
    }
    __syncthreads();
    if (ihalf == 0) {
        const unsigned* srcp = &wlds[(btile * 64 + lane) * 32];
        const float sc = use_osum ? 1.0f : 0.0625f;
#pragma unroll
        for (int jq = 0; jq < 4; ++jq) {
            const int j = 4 * jq + g;
#pragma unroll
            for (int q = 0; q < 4; ++q) {
                half2v ha = __builtin_bit_cast(half2v, srcp[(jq * 4 + q) * 2]);
                half2v hb = __builtin_bit_cast(half2v, srcp[(jq * 4 + q) * 2 + 1]);
                float s0 = (acc[jq][q][0] + (float)ha.x) * sc;
                float s1 = (acc[jq][q][1] + (float)ha.y) * sc;
                float s2 = (acc[jq][q][2] + (float)hb.x) * sc;
                float s3 = (acc[jq][q][3] + (float)hb.y) * sc;
                *(uint2*)&partials[(size_t)ib * (B_ * NC_ * 8) +
                                   ((size_t)b16 * 16 + j) * 8 + q * 2] =
                    make_uint2(pk16(s0, s1), pk16(s2, s3));
            }
        }
    }
}

// Reduce over NI i-blocks (f16 partials) + squash — unchanged (R16-verified).
// mode 0: osum = out ; mode 1: osum += out ; mode 2: d_out = out
__global__ __launch_bounds__(256)
void caps_reduce(const unsigned* __restrict__ partials, float* __restrict__ osum,
                 float* __restrict__ outb, int NI, int mode)
{
    __shared__ float4 red[256];
    const int tid = threadIdx.x;
    const int q   = tid & 3;
    const int ks  = tid >> 2;
    const int bj  = blockIdx.x;

    float4 s = make_float4(0.f, 0.f, 0.f, 0.f);
    for (int ibk = ks; ibk < NI; ibk += 64) {
        uint2 v = *(const uint2*)&partials[(size_t)ibk * (B_ * NC_ * 8) +
                                           (size_t)bj * 8 + q * 2];
        half2v h0 = __builtin_bit_cast(half2v, v.x);
        half2v h1 = __builtin_bit_cast(half2v, v.y);
        s.x += (float)h0.x; s.y += (float)h0.y;
        s.z += (float)h1.x; s.w += (float)h1.y;
    }
    red[tid] = s;
    __syncthreads();
    if (tid < 64) {
        float4 a = red[tid], b = red[tid + 64], cc = red[tid + 128], d = red[tid + 192];
        s.x = a.x + b.x + cc.x + d.x; s.y = a.y + b.y + cc.y + d.y;
        s.z = a.z + b.z + cc.z + d.z; s.w = a.w + b.w + cc.w + d.w;
        red[tid] = s;
    }
    __syncthreads();
    if (tid < 4) {
        float4 t = red[tid];
#pragma unroll
        for (int kk = 1; kk < 16; ++kk) {
            float4 v = red[kk * 4 + tid];
            t.x += v.x; t.y += v.y; t.z += v.z; t.w += v.w;
        }
        float s2 = t.x * t.x + t.y * t.y + t.z * t.z + t.w * t.w;
        s2 += __shfl_xor(s2, 1);
        s2 += __shfl_xor(s2, 2);
        float scale = s2 / (1.0f + s2) * rsqrtf(s2 + 1e-7f);
        float4 o = make_float4(scale * t.x, scale * t.y, scale * t.z, scale * t.w);
        size_t fi = (size_t)bj * 4 + tid;
        if (mode == 0) ((float4*)osum)[fi] = o;
        else if (mode == 1) {
            float4 cu = ((float4*)osum)[fi];
            cu.x += o.x; cu.y += o.y; cu.z += o.z; cu.w += o.w;
            ((float4*)osum)[fi] = cu;
        } else ((float4*)outb)[fi] = o;
    }
}

extern "C" void kernel_launch(void* const* d_in, const int* in_sizes, int n_in,
                              void* d_out, int out_size, void* d_ws, size_t ws_size,
                              hipStream_t stream)
{
    const float* inp = (const float*)d_in[0];  // [64, 4096, 8]
    const float* W   = (const float*)d_in[1];  // [16, 4096, 16, 8]
    float* out  = (float*)d_out;               // [64, 16, 16]

    float*    osum     = (float*)d_ws;                      // 16 KB used
    unsigned* partials = (unsigned*)((char*)d_ws + 65536);  // NI*32KB = 16.8 MB

    const int NI = IC_ / IPB;      // 512
    dim3 grid(NI);                 // 512 blocks x 512 thr

    // iter 0: uniform c (MFMA, no softmax)
    caps_mpass<<<grid, 512, 0, stream>>>(inp, W, osum, partials, 0);
    caps_reduce<<<1024, 256, 0, stream>>>(partials, osum, out, NI, 0);
    // iter 1: logits = out0 . u_hat
    caps_mpass<<<grid, 512, 0, stream>>>(inp, W, osum, partials, 1);
    caps_reduce<<<1024, 256, 0, stream>>>(partials, osum, out, NI, 1);
    // iter 2: logits = (out0 + out1) . u_hat
    caps_mpass<<<grid, 512, 0, stream>>>(inp, W, osum, partials, 1);
    caps_reduce<<<1024, 256, 0, stream>>>(partials, osum, out, NI, 2);
}

// Round 20
// 107.280 us; speedup vs baseline: 1.5286x; 1.5286x over previous
//
#include <hip/hip_runtime.h>
#include <math.h>

// Problem constants
#define B_   64
#define IC_  4096
#define NC_  16
#define D_   16
#define IPB  16    // i's per block (NI = 256 i-blocks)
#define CH_  2     // i's per double-buffered W chunk
#define WROW 68    // u32 per W-LDS row: 64 data (128 f16) + 4 pad
#define XROW 68    // u32 per x-LDS batch row: 64 data + 4 pad

typedef __fp16 half8  __attribute__((ext_vector_type(8)));
typedef __fp16 half2v __attribute__((ext_vector_type(2)));
typedef float  f32x4  __attribute__((ext_vector_type(4)));

#if __has_builtin(__builtin_amdgcn_fdot2)
#define HAVE_FDOT2 1
#else
#define HAVE_FDOT2 0
#endif

// pack 2 fp32 -> half2 in a u32 (v_cvt_pkrtz_f32_f16)
__device__ inline unsigned pk16(float a, float b) {
    half2v h = __builtin_amdgcn_cvt_pkrtz(a, b);
    return __builtin_bit_cast(unsigned, h);
}
// f32 += dot(half2, half2)  (v_dot2_f32_f16)
__device__ inline float hdot2(unsigned w, unsigned x, float cacc) {
#if HAVE_FDOT2
    return __builtin_amdgcn_fdot2(__builtin_bit_cast(half2v, w),
                                  __builtin_bit_cast(half2v, x), cacc, false);
#else
    half2v hw = __builtin_bit_cast(half2v, w);
    half2v hx = __builtin_bit_cast(half2v, x);
    return cacc + (float)hw.x * (float)hx.x + (float)hw.y * (float)hx.y;
#endif
}
__device__ inline half8 h8(uint4 v) { return __builtin_bit_cast(half8, v); }

// Sum-rotate within 16-lane DPP rows (j dim) on the VALU pipe.
template <int CTRL>
__device__ inline float ror_add(float v) {
    int r = __builtin_amdgcn_update_dpp(0, __float_as_int(v), CTRL, 0xf, 0xf, false);
    return v + __int_as_float(r);
}

// ---------------- pass0: uniform-c MFMA GEMM (depth-4 prefetch) ----------------
// S0[b,j,d] = (1/16) sum_{i,e} W[j,i,d,e] x[b,i,e].  K packs (4 i x 8 e) = 32.
// Block = 512 thr (8 waves), one 16-i slice; wave wv owns j in {2wv, 2wv+1}.
// ALL 16 A-fragment float4 loads hoisted before the MFMA loop: one vmcnt
// drain (shared with the x barrier), then 32 MFMAs from registers.
// Layouts HW-verified R17/R18: A lane = W[j, i=kc*4+g, d=l15, e0..7];
// B lane = x[b=bt*16+l15, i=kc*4+g, e0..7]; C col=l15 (b), row=g*4+reg (d).
__global__ __launch_bounds__(512)
void caps_pass0(const float* __restrict__ inp, const float* __restrict__ W,
                unsigned* __restrict__ partials)
{
    __shared__ unsigned xlds[64 * XROW];  // 17408 B

    const int tid  = threadIdx.x;
    const int lane = tid & 63;
    const int l15  = lane & 15;
    const int g    = lane >> 4;
    const int wv   = tid >> 6;

    // XCD-aware swizzle (grid 256, divisible by 8)
    const int n   = blockIdx.x;
    const int cpx = gridDim.x >> 3;
    const int ib  = (n & 7) * cpx + (n >> 3);
    const int i0  = ib * IPB;

    // stage x f16: [64 b][16 i][4 u32]; thread t: b = t>>3, two i's
    {
        const int xb = tid >> 3;
        const int io = (tid & 7) * 2;
#pragma unroll
        for (int r = 0; r < 2; ++r) {
            const float4* src =
                (const float4*)inp + ((size_t)xb * IC_ + i0 + io + r) * 2;
            float4 a = src[0], b = src[1];
            *(uint4*)&xlds[xb * XROW + (io + r) * 4] =
                make_uint4(pk16(a.x, a.y), pk16(a.z, a.w),
                           pk16(b.x, b.y), pk16(b.z, b.w));
        }
    }

    // hoist ALL W loads (16 float4/thread) — they drain at the barrier below
    const int j0 = wv * 2;
    float4 wr[4][2][2];
#pragma unroll
    for (int kc = 0; kc < 4; ++kc)
#pragma unroll
        for (int jj = 0; jj < 2; ++jj) {
            const float4* wp = (const float4*)W +
                (((size_t)(j0 + jj) * IC_ + i0 + kc * 4 + g) * 16 + l15) * 2;
            wr[kc][jj][0] = wp[0];
            wr[kc][jj][1] = wp[1];
        }
    __syncthreads();

    f32x4 acc[2][4];
#pragma unroll
    for (int jj = 0; jj < 2; ++jj)
#pragma unroll
        for (int bt = 0; bt < 4; ++bt) acc[jj][bt] = (f32x4){0.f, 0.f, 0.f, 0.f};

#pragma unroll
    for (int kc = 0; kc < 4; ++kc) {
        half8 af[2];
#pragma unroll
        for (int jj = 0; jj < 2; ++jj) {
            float4 a = wr[kc][jj][0], b = wr[kc][jj][1];
            af[jj] = h8(make_uint4(pk16(a.x, a.y), pk16(a.z, a.w),
                                   pk16(b.x, b.y), pk16(b.z, b.w)));
        }
#pragma unroll
        for (int bt = 0; bt < 4; ++bt) {
            uint4 xf = *(const uint4*)&xlds[(bt * 16 + l15) * XROW + (kc * 4 + g) * 4];
            half8 bfrag = h8(xf);
#pragma unroll
            for (int jj = 0; jj < 2; ++jj)
                acc[jj][bt] = __builtin_amdgcn_mfma_f32_16x16x32_f16(
                    af[jj], bfrag, acc[jj][bt], 0, 0, 0);
        }
    }

    // epilogue: lane -> (b = bt*16+l15, j = j0+jj, d-quad = g); scale 1/16
#pragma unroll
    for (int jj = 0; jj < 2; ++jj)
#pragma unroll
        for (int bt = 0; bt < 4; ++bt) {
            f32x4 C = acc[jj][bt];
            unsigned lo = pk16(C[0] * 0.0625f, C[1] * 0.0625f);
            unsigned hi = pk16(C[2] * 0.0625f, C[3] * 0.0625f);
            size_t b = bt * 16 + l15;
            *(uint2*)&partials[(size_t)ib * (B_ * NC_ * 8) +
                               (b * 16 + (j0 + jj)) * 8 + g * 2] =
                make_uint2(lo, hi);
        }
}

// ---------------- sweep pass (R16/R18 verbatim) ----------------
__global__ __launch_bounds__(512, 4)
void caps_pass(const float* __restrict__ inp, const float* __restrict__ W,
               const float* __restrict__ osum, unsigned* __restrict__ partials,
               int use_osum)
{
    __shared__ unsigned wlds[2][CH_ * NC_ * WROW];  // 17408 B
    __shared__ unsigned xlds[32 * XROW];            // 8704 B

    const int tid = threadIdx.x;
    const int j   = tid & 15;
    const int c   = (tid >> 4) & 3;
    const int wv  = tid >> 6;

    const int n   = blockIdx.x;
    const int cpx = gridDim.x >> 3;
    const int wg  = (n & 7) * cpx + (n >> 3);
    const int ib  = wg >> 1;
    const int bg  = wg & 1;
    const int i0  = ib * IPB;
    const int b0  = bg * 32 + wv * 4;

    {
        const int xb = tid >> 4, xil = tid & 15;
        const float4* src =
            (const float4*)inp + ((size_t)(bg * 32 + xb) * IC_ + i0 + xil) * 2;
        float4 xa = src[0], xbv = src[1];
        *(uint4*)&xlds[xb * XROW + xil * 4] =
            make_uint4(pk16(xa.x, xa.y), pk16(xa.z, xa.w),
                       pk16(xbv.x, xbv.y), pk16(xbv.z, xbv.w));
    }

    const int srow = tid >> 4;
    const int scol = tid & 15;
    const int sil  = srow >> 4;
    const int sj   = srow & 15;
    const float4* Wf4 = (const float4*)W;
    const size_t wgbase = ((size_t)sj * IC_) * 32 + scol * 2;

    float4 g0, g1;
    g0 = Wf4[wgbase + (size_t)(i0 + sil) * 32];
    g1 = Wf4[wgbase + (size_t)(i0 + sil) * 32 + 1];
    *(uint4*)&wlds[0][srow * WROW + scol * 4] =
        make_uint4(pk16(g0.x, g0.y), pk16(g0.z, g0.w),
                   pk16(g1.x, g1.y), pk16(g1.z, g1.w));
    __syncthreads();

    float4 os[4];
    if (use_osum) {
#pragma unroll
        for (int bi = 0; bi < 4; ++bi) {
            float4 o = ((const float4*)osum)[((size_t)(b0 + bi) * 16 + j) * 4 + c];
            const float L2E = 1.44269504f;
            os[bi] = make_float4(o.x * L2E, o.y * L2E, o.z * L2E, o.w * L2E);
        }
    }

    float acc[4][4];
#pragma unroll
    for (int bi = 0; bi < 4; ++bi)
#pragma unroll
        for (int dl = 0; dl < 4; ++dl) acc[bi][dl] = 0.0f;

    const int nch = IPB / CH_;
    int cur = 0;
    for (int ch = 0; ch < nch; ++ch) {
        if (ch + 1 < nch) {
            const int inx = i0 + (ch + 1) * CH_ + sil;
            g0 = Wf4[wgbase + (size_t)inx * 32];
            g1 = Wf4[wgbase + (size_t)inx * 32 + 1];
        }
#pragma unroll
        for (int il = 0; il < CH_; ++il) {
            const int ilg = ch * CH_ + il;
            const unsigned* wr = &wlds[cur][(il * NC_ + j) * WROW + c * 16];
            uint4 q0 = *(const uint4*)&wr[0];
            uint4 q1 = *(const uint4*)&wr[4];
            uint4 q2 = *(const uint4*)&wr[8];
            uint4 q3 = *(const uint4*)&wr[12];

            uint4 xh[4];
#pragma unroll
            for (int bi = 0; bi < 4; ++bi)
                xh[bi] = *(const uint4*)&xlds[(wv * 4 + bi) * XROW + ilg * 4];

            float uh[4][4];
#pragma unroll
            for (int dl = 0; dl < 4; ++dl) {
                uint4 qq = (dl == 0) ? q0 : (dl == 1) ? q1 : (dl == 2) ? q2 : q3;
#pragma unroll
                for (int bi = 0; bi < 4; ++bi) {
                    float r = hdot2(qq.x, xh[bi].x, 0.0f);
                    r = hdot2(qq.y, xh[bi].y, r);
                    r = hdot2(qq.z, xh[bi].z, r);
                    uh[bi][dl] = hdot2(qq.w, xh[bi].w, r);
                }
            }

            float cc[4];
            if (use_osum) {
                float pb[4];
#pragma unroll
                for (int bi = 0; bi < 4; ++bi) {
                    float t = os[bi].x * uh[bi][0];
                    t = fmaf(os[bi].y, uh[bi][1], t);
                    t = fmaf(os[bi].z, uh[bi][2], t);
                    t = fmaf(os[bi].w, uh[bi][3], t);
                    pb[bi] = t;
                }
#pragma unroll
                for (int bi = 0; bi < 4; ++bi) {
                    pb[bi] += __shfl_xor(pb[bi], 16);
                    pb[bi] += __shfl_xor(pb[bi], 32);
                }
#pragma unroll
                for (int bi = 0; bi < 4; ++bi) {
                    float e  = exp2f(pb[bi]);
                    float sm = ror_add<0x128>(e);
                    sm = ror_add<0x124>(sm);
                    sm = ror_add<0x122>(sm);
                    sm = ror_add<0x121>(sm);
                    cc[bi] = __fdividef(e, sm);
                }
            } else {
#pragma unroll
                for (int bi = 0; bi < 4; ++bi) cc[bi] = 0.0625f;
            }

#pragma unroll
            for (int bi = 0; bi < 4; ++bi)
#pragma unroll
                for (int dl = 0; dl < 4; ++dl)
                    acc[bi][dl] = fmaf(cc[bi], uh[bi][dl], acc[bi][dl]);
        }
        if (ch + 1 < nch) {
            const int nb = cur ^ 1;
            *(uint4*)&wlds[nb][srow * WROW + scol * 4] =
                make_uint4(pk16(g0.x, g0.y), pk16(g0.z, g0.w),
                           pk16(g1.x, g1.y), pk16(g1.z, g1.w));
        }
        __syncthreads();
        cur ^= 1;
    }

#pragma unroll
    for (int bi = 0; bi < 4; ++bi) {
        unsigned lo = pk16(acc[bi][0], acc[bi][1]);
        unsigned hi = pk16(acc[bi][2], acc[bi][3]);
        *(uint2*)&partials[(size_t)ib * (B_ * NC_ * 8) +
                           ((size_t)(b0 + bi) * NC_ + j) * 8 + c * 2] =
            make_uint2(lo, hi);
    }
}

// ---------------- reduce (R16 verbatim) ----------------
__global__ __launch_bounds__(256)
void caps_reduce(const unsigned* __restrict__ partials, float* __restrict__ osum,
                 float* __restrict__ outb, int NI, int mode)
{
    __shared__ float4 red[256];
    const int tid = threadIdx.x;
    const int q   = tid & 3;
    const int ks  = tid >> 2;
    const int bj  = blockIdx.x;

    float4 s = make_float4(0.f, 0.f, 0.f, 0.f);
    for (int ibk = ks; ibk < NI; ibk += 64) {
        uint2 v = *(const uint2*)&partials[(size_t)ibk * (B_ * NC_ * 8) +
                                           (size_t)bj * 8 + q * 2];
        half2v h0 = __builtin_bit_cast(half2v, v.x);
        half2v h1 = __builtin_bit_cast(half2v, v.y);
        s.x += (float)h0.x; s.y += (float)h0.y;
        s.z += (float)h1.x; s.w += (float)h1.y;
    }
    red[tid] = s;
    __syncthreads();
    if (tid < 64) {
        float4 a = red[tid], b = red[tid + 64], cc = red[tid + 128], d = red[tid + 192];
        s.x = a.x + b.x + cc.x + d.x; s.y = a.y + b.y + cc.y + d.y;
        s.z = a.z + b.z + cc.z + d.z; s.w = a.w + b.w + cc.w + d.w;
        red[tid] = s;
    }
    __syncthreads();
    if (tid < 4) {
        float4 t = red[tid];
#pragma unroll
        for (int kk = 1; kk < 16; ++kk) {
            float4 v = red[kk * 4 + tid];
            t.x += v.x; t.y += v.y; t.z += v.z; t.w += v.w;
        }
        float s2 = t.x * t.x + t.y * t.y + t.z * t.z + t.w * t.w;
        s2 += __shfl_xor(s2, 1);
        s2 += __shfl_xor(s2, 2);
        float scale = s2 / (1.0f + s2) * rsqrtf(s2 + 1e-7f);
        float4 o = make_float4(scale * t.x, scale * t.y, scale * t.z, scale * t.w);
        size_t fi = (size_t)bj * 4 + tid;
        if (mode == 0) ((float4*)osum)[fi] = o;
        else if (mode == 1) {
            float4 cu = ((float4*)osum)[fi];
            cu.x += o.x; cu.y += o.y; cu.z += o.z; cu.w += o.w;
            ((float4*)osum)[fi] = cu;
        } else ((float4*)outb)[fi] = o;
    }
}

extern "C" void kernel_launch(void* const* d_in, const int* in_sizes, int n_in,
                              void* d_out, int out_size, void* d_ws, size_t ws_size,
                              hipStream_t stream)
{
    const float* inp = (const float*)d_in[0];  // [64, 4096, 8]
    const float* W   = (const float*)d_in[1];  // [16, 4096, 16, 8]
    float* out  = (float*)d_out;               // [64, 16, 16]

    float*    osum     = (float*)d_ws;                      // 16 KB used
    unsigned* partials = (unsigned*)((char*)d_ws + 65536);  // NI*32KB = 8.4 MB

    const int NI = IC_ / IPB;      // 256
    dim3 grid(2 * NI);             // 512 blocks (sweep passes)

    // iter 0: uniform c -> K-packed MFMA GEMM (prefetch-all)
    caps_pass0<<<NI, 512, 0, stream>>>(inp, W, partials);
    caps_reduce<<<1024, 256, 0, stream>>>(partials, osum, out, NI, 0);
    // iter 1: logits = out0 . u_hat
    caps_pass<<<grid, 512, 0, stream>>>(inp, W, osum, partials, 1);
    caps_reduce<<<1024, 256, 0, stream>>>(partials, osum, out, NI, 1);
    // iter 2: logits = (out0 + out1) . u_hat
    caps_pass<<<grid, 512, 0, stream>>>(inp, W, osum, partials, 1);
    caps_reduce<<<1024, 256, 0, stream>>>(partials, osum, out, NI, 2);
}